// Round 5
// baseline (336.501 us; speedup 1.0000x reference)
//
#include <hip/hip_runtime.h>
#include <math.h>

#define B_   8
#define C_   256
#define CI_  128
#define N_   1024
#define HW_  32
#define CO_  256

typedef __bf16 v8bf __attribute__((ext_vector_type(8)));
typedef float  f32x4 __attribute__((ext_vector_type(4)));
typedef unsigned short ushort_t;

__device__ __forceinline__ unsigned short f2bf_rne(float f) {
    unsigned int u = __float_as_uint(f);
    unsigned int r = u + 0x7FFF + ((u >> 16) & 1);
    return (unsigned short)(r >> 16);
}
__device__ __forceinline__ float bf2f(unsigned short h) {
    return __uint_as_float(((unsigned int)h) << 16);
}
__device__ __forceinline__ v8bf ld8(const ushort_t* p) {
    return *(const v8bf*)p;
}

// ---------------------------------------------------------------------------
// P1: split Wc into bf16 hi/lo [o][tap][ci]  AND  Wq/Wk/Wv into Wp hi/lo [384][256]
__global__ __launch_bounds__(256) void prep_w_kernel(
    const float* __restrict__ Wc,
    const float* __restrict__ Wq, const float* __restrict__ Wk,
    const float* __restrict__ Wv,
    ushort_t* __restrict__ Whi, ushort_t* __restrict__ Wlo,
    ushort_t* __restrict__ Wp_hi, ushort_t* __restrict__ Wp_lo)
{
    if (blockIdx.x < 1152) {
        int idx = blockIdx.x * 256 + threadIdx.x;     // 294912
        int o = idx / 1152;
        int r = idx - o * 1152;
        int ci = r / 9;
        int tap = r - ci * 9;
        float v = Wc[idx];
        unsigned short h = f2bf_rne(v);
        unsigned short l = f2bf_rne(v - bf2f(h));
        int didx = o * 1152 + tap * 128 + ci;
        Whi[didx] = h; Wlo[didx] = l;
    } else {
        int j = (blockIdx.x - 1152) * 256 + threadIdx.x;  // 98304
        int o = j >> 8, c = j & 255;
        float v = (o < 128) ? Wq[o * 256 + c]
                : (o < 256) ? Wk[(o - 128) * 256 + c]
                            : Wv[(o - 256) * 256 + c];
        unsigned short h = f2bf_rne(v);
        unsigned short l = f2bf_rne(v - bf2f(h));
        Wp_hi[j] = h; Wp_lo[j] = l;
    }
}

// ---------------------------------------------------------------------------
// P2: gather strided x -> xs_t[b][n][c] bf16 hi/lo (transposed via LDS)
__global__ __launch_bounds__(256) void prep_x_kernel(
    const float* __restrict__ x,
    ushort_t* __restrict__ xs_hi, ushort_t* __restrict__ xs_lo)
{
    __shared__ ushort_t lh[32 * 264];
    __shared__ ushort_t ll[32 * 264];
    const int h = blockIdx.x, b = blockIdx.y;
    const int tid = threadIdx.x;
    const int w = tid & 31, cg = tid >> 5;
    for (int c0 = 0; c0 < 256; c0 += 8) {
        int c = c0 + cg;
        float v = x[((size_t)(b * C_ + c) * 128 + h * 4) * 128 + w * 4];
        unsigned short hi = f2bf_rne(v);
        unsigned short lo = f2bf_rne(v - bf2f(hi));
        lh[w * 264 + c] = hi;
        ll[w * 264 + c] = lo;
    }
    __syncthreads();
    const int ww = tid >> 3, cs = tid & 7;
    size_t dst = ((size_t)(b * N_) + h * 32 + ww) * 256 + cs * 32;
    #pragma unroll
    for (int t = 0; t < 4; ++t) {
        *(uint4*)&xs_hi[dst + t * 8] = *(uint4*)&lh[ww * 264 + cs * 32 + t * 8];
        *(uint4*)&xs_lo[dst + t * 8] = *(uint4*)&ll[ww * 264 + cs * 32 + t * 8];
    }
}

// ---------------------------------------------------------------------------
// K1: proj MFMA. A = Wp [o][c] hi/lo, B = xs_t [n][c] hi/lo. 3-term split.
// Writes q,k transposed [n][o] hi/lo; v in packed layout vB[b][m>>5][c][m&31].
__global__ __launch_bounds__(256) void proj_mfma_kernel(
    const ushort_t* __restrict__ Wp_hi, const ushort_t* __restrict__ Wp_lo,
    const ushort_t* __restrict__ xs_hi, const ushort_t* __restrict__ xs_lo,
    ushort_t* __restrict__ qt_hi, ushort_t* __restrict__ qt_lo,
    ushort_t* __restrict__ kt_hi, ushort_t* __restrict__ kt_lo,
    ushort_t* __restrict__ vB_hi, ushort_t* __restrict__ vB_lo)
{
    const int n0 = blockIdx.x * 64;
    const int o0 = blockIdx.y * 64;
    const int b  = blockIdx.z;
    const int tid = threadIdx.x;
    const int l = tid & 63, wv = tid >> 6;
    const int wy = wv >> 1, wx = wv & 1;
    const int ln = l & 15, quad = l >> 4;

    f32x4 acc[2][2];
    #pragma unroll
    for (int i = 0; i < 2; ++i)
        #pragma unroll
        for (int j = 0; j < 2; ++j) acc[i][j] = (f32x4){0.f,0.f,0.f,0.f};

    const ushort_t* Ah_p[2]; const ushort_t* Al_p[2];
    const ushort_t* Bh_p[2]; const ushort_t* Bl_p[2];
    #pragma unroll
    for (int i = 0; i < 2; ++i) {
        size_t off = (size_t)(o0 + wy * 32 + i * 16 + ln) * 256 + quad * 8;
        Ah_p[i] = Wp_hi + off; Al_p[i] = Wp_lo + off;
    }
    #pragma unroll
    for (int j = 0; j < 2; ++j) {
        size_t off = ((size_t)(b * N_) + n0 + wx * 32 + j * 16 + ln) * 256 + quad * 8;
        Bh_p[j] = xs_hi + off; Bl_p[j] = xs_lo + off;
    }

    #pragma unroll 4
    for (int k0 = 0; k0 < 256; k0 += 32) {
        v8bf Ah[2], Al[2], Bh[2], Bl[2];
        #pragma unroll
        for (int i = 0; i < 2; ++i) { Ah[i] = ld8(Ah_p[i] + k0); Al[i] = ld8(Al_p[i] + k0); }
        #pragma unroll
        for (int j = 0; j < 2; ++j) { Bh[j] = ld8(Bh_p[j] + k0); Bl[j] = ld8(Bl_p[j] + k0); }
        #pragma unroll
        for (int i = 0; i < 2; ++i)
            #pragma unroll
            for (int j = 0; j < 2; ++j) {
                acc[i][j] = __builtin_amdgcn_mfma_f32_16x16x32_bf16(Ah[i], Bh[j], acc[i][j], 0, 0, 0);
                acc[i][j] = __builtin_amdgcn_mfma_f32_16x16x32_bf16(Ah[i], Bl[j], acc[i][j], 0, 0, 0);
                acc[i][j] = __builtin_amdgcn_mfma_f32_16x16x32_bf16(Al[i], Bh[j], acc[i][j], 0, 0, 0);
            }
    }

    if (o0 < 256) {
        ushort_t* th = (o0 < 128) ? qt_hi : kt_hi;
        ushort_t* tl = (o0 < 128) ? qt_lo : kt_lo;
        const int ob = o0 & 127;
        #pragma unroll
        for (int i = 0; i < 2; ++i)
            #pragma unroll
            for (int j = 0; j < 2; ++j) {
                int oo = ob + wy * 32 + i * 16 + quad * 4;
                int n  = n0 + wx * 32 + j * 16 + ln;
                unsigned int h01 = 0, h23 = 0, l01 = 0, l23 = 0;
                #pragma unroll
                for (int r = 0; r < 4; ++r) {
                    float f = acc[i][j][r];
                    unsigned short hh = f2bf_rne(f);
                    unsigned short lo = f2bf_rne(f - bf2f(hh));
                    if (r < 2) { h01 |= ((unsigned)hh) << (16 * r); l01 |= ((unsigned)lo) << (16 * r); }
                    else       { h23 |= ((unsigned)hh) << (16 * (r - 2)); l23 |= ((unsigned)lo) << (16 * (r - 2)); }
                }
                size_t off = ((size_t)(b * N_) + n) * 128 + oo;
                *(uint2*)&th[off] = make_uint2(h01, h23);
                *(uint2*)&tl[off] = make_uint2(l01, l23);
            }
    } else {
        #pragma unroll
        for (int i = 0; i < 2; ++i)
            #pragma unroll
            for (int j = 0; j < 2; ++j)
                #pragma unroll
                for (int r = 0; r < 4; ++r) {
                    int c = (o0 - 256) + wy * 32 + i * 16 + quad * 4 + r;
                    int m = n0 + wx * 32 + j * 16 + ln;
                    float f = acc[i][j][r];
                    unsigned short hh = f2bf_rne(f);
                    unsigned short lo = f2bf_rne(f - bf2f(hh));
                    size_t off = (((size_t)b * 32 + (m >> 5)) * 128 + c) * 32 + (m & 31);
                    vB_hi[off] = hh; vB_lo[off] = lo;
                }
    }
}

// ---------------------------------------------------------------------------
// K2: fused attention, 16-row n-strips (512 blocks, 2/CU).
// Phase 1: S[16][1024] in regs (16 mtiles/wave). Softmax. gate write.
// Phase 2: gv[128][16] from 32KB LDS bf16 gate tile; fused mean via atomics.
__global__ __launch_bounds__(256, 2) void attn_fused_kernel(
    const ushort_t* __restrict__ qt_hi, const ushort_t* __restrict__ qt_lo,
    const ushort_t* __restrict__ kt_hi, const ushort_t* __restrict__ kt_lo,
    const ushort_t* __restrict__ vB_hi, const ushort_t* __restrict__ vB_lo,
    float* __restrict__ gate, float* __restrict__ gv, float* __restrict__ meanb)
{
    __shared__ __align__(16) char gsm[32768];     // Gbf[16][1024] bf16, 16B-chunk XOR swizzle
    __shared__ float redA[4][16];
    __shared__ float redB[4][16];

    const int n0 = blockIdx.x * 16;
    const int b  = blockIdx.y;
    const int tid = threadIdx.x;
    const int l = tid & 63, w = tid >> 6;
    const int ln = l & 15, quad = l >> 4;
    const int Mw = w * 256;

    const ushort_t* qb_h = qt_hi + ((size_t)(b * N_) + n0) * 128;
    const ushort_t* qb_l = qt_lo + ((size_t)(b * N_) + n0) * 128;
    const ushort_t* kb_h = kt_hi + (size_t)(b * N_) * 128;
    const ushort_t* kb_l = kt_lo + (size_t)(b * N_) * 128;

    f32x4 acc[16];
    #pragma unroll
    for (int mt = 0; mt < 16; ++mt) acc[mt] = (f32x4){0.f,0.f,0.f,0.f};

    // ---- phase 1: scores
    #pragma unroll
    for (int c0 = 0; c0 < 128; c0 += 32) {
        size_t aoff = (size_t)ln * 128 + c0 + quad * 8;
        v8bf Ah = ld8(qb_h + aoff);
        v8bf Al = ld8(qb_l + aoff);
        #pragma unroll
        for (int mt = 0; mt < 16; ++mt) {
            size_t boff = (size_t)(Mw + mt * 16 + ln) * 128 + c0 + quad * 8;
            v8bf Bh = ld8(kb_h + boff);
            v8bf Bl = ld8(kb_l + boff);
            acc[mt] = __builtin_amdgcn_mfma_f32_16x16x32_bf16(Ah, Bh, acc[mt], 0, 0, 0);
            acc[mt] = __builtin_amdgcn_mfma_f32_16x16x32_bf16(Ah, Bl, acc[mt], 0, 0, 0);
            acc[mt] = __builtin_amdgcn_mfma_f32_16x16x32_bf16(Al, Bh, acc[mt], 0, 0, 0);
        }
    }

    // ---- softmax: row n = quad*4+r, col m = Mw+mt*16+ln
    float rmax[4];
    #pragma unroll
    for (int r = 0; r < 4; ++r) {
        float m = acc[0][r];
        #pragma unroll
        for (int mt = 1; mt < 16; ++mt) m = fmaxf(m, acc[mt][r]);
        #pragma unroll
        for (int xm = 1; xm <= 8; xm <<= 1) m = fmaxf(m, __shfl_xor(m, xm, 64));
        rmax[r] = m;
    }
    if (ln == 0) {
        #pragma unroll
        for (int r = 0; r < 4; ++r) redA[w][quad * 4 + r] = rmax[r];
    }
    __syncthreads();
    #pragma unroll
    for (int r = 0; r < 4; ++r) {
        int row = quad * 4 + r;
        rmax[r] = fmaxf(fmaxf(redA[0][row], redA[1][row]),
                        fmaxf(redA[2][row], redA[3][row]));
    }

    float rsum[4];
    #pragma unroll
    for (int r = 0; r < 4; ++r) {
        float s = 0.f;
        #pragma unroll
        for (int mt = 0; mt < 16; ++mt) {
            float e = __expf(acc[mt][r] - rmax[r]);
            acc[mt][r] = e;
            s += e;
        }
        #pragma unroll
        for (int xm = 1; xm <= 8; xm <<= 1) s += __shfl_xor(s, xm, 64);
        rsum[r] = s;
    }
    if (ln == 0) {
        #pragma unroll
        for (int r = 0; r < 4; ++r) redB[w][quad * 4 + r] = rsum[r];
    }
    __syncthreads();
    #pragma unroll
    for (int r = 0; r < 4; ++r) {
        int row = quad * 4 + r;
        float inv = 1.0f / (redB[0][row] + redB[1][row] + redB[2][row] + redB[3][row]);
        #pragma unroll
        for (int mt = 0; mt < 16; ++mt) acc[mt][r] *= inv;
    }

    // ---- write gate fp32 + bf16 -> swizzled LDS
    float* grow = gate + (size_t)b * N_ * N_;
    #pragma unroll
    for (int r = 0; r < 4; ++r) {
        int nl = quad * 4 + r;
        int n  = n0 + nl;
        #pragma unroll
        for (int mt = 0; mt < 16; ++mt) {
            int m = Mw + mt * 16 + ln;
            float v = acc[mt][r];
            grow[(size_t)n * N_ + m] = v;
            int chunk = m >> 3;
            int addr = nl * 2048 + (((chunk ^ (nl & 7))) << 4) + ((m & 7) << 1);
            *(ushort_t*)&gsm[addr] = f2bf_rne(v);
        }
    }
    __syncthreads();

    // ---- phase 2: gv[c][n] = sum_m gate[n][m]*v[c][m]
    const ushort_t* vb_h = vB_hi + (size_t)b * CI_ * N_;
    const ushort_t* vb_l = vB_lo + (size_t)b * CI_ * N_;

    f32x4 acc2[2];
    acc2[0] = (f32x4){0.f,0.f,0.f,0.f};
    acc2[1] = (f32x4){0.f,0.f,0.f,0.f};

    #pragma unroll 4
    for (int m0 = 0; m0 < 1024; m0 += 32) {
        int nl = ln;
        int chunk = (m0 >> 3) + quad;
        v8bf Bg = *(const v8bf*)&gsm[nl * 2048 + (((chunk ^ (nl & 7))) << 4)];
        #pragma unroll
        for (int ct = 0; ct < 2; ++ct) {
            int c = w * 32 + ct * 16 + ln;
            size_t aoff = (((size_t)(m0 >> 5)) * 128 + c) * 32 + quad * 8;
            v8bf Avh = ld8(vb_h + aoff);
            v8bf Avl = ld8(vb_l + aoff);
            acc2[ct] = __builtin_amdgcn_mfma_f32_16x16x32_bf16(Avh, Bg, acc2[ct], 0, 0, 0);
            acc2[ct] = __builtin_amdgcn_mfma_f32_16x16x32_bf16(Avl, Bg, acc2[ct], 0, 0, 0);
        }
    }

    // write gv + fused mean (atomicAdd per c over this 16-n strip)
    #pragma unroll
    for (int ct = 0; ct < 2; ++ct)
        #pragma unroll
        for (int r = 0; r < 4; ++r) {
            int c = w * 32 + ct * 16 + quad * 4 + r;
            int n = n0 + ln;
            float v = acc2[ct][r];
            gv[(size_t)(b * CI_ + c) * N_ + n] = v;
            float s = v;
            #pragma unroll
            for (int xm = 1; xm <= 8; xm <<= 1) s += __shfl_xor(s, xm, 64);
            if (ln == 0)
                atomicAdd(&meanb[b * CI_ + c], s * (1.0f / 1024.0f));
        }
}

// ---------------------------------------------------------------------------
// K6: conv1d + sigmoid
__global__ __launch_bounds__(1024) void ca_kernel(
    const float* __restrict__ meanb, const float* __restrict__ w1d,
    float* __restrict__ ca)
{
    const int t = threadIdx.x;
    const int i = t & 127;
    float left  = (i > 0)   ? meanb[t - 1] : 0.0f;
    float mid   = meanb[t];
    float right = (i < 127) ? meanb[t + 1] : 0.0f;
    float val = w1d[0] * left + w1d[1] * mid + w1d[2] * right;
    ca[t] = 1.0f / (1.0f + __expf(-val));
}

// ---------------------------------------------------------------------------
// K7: MFMA conv v2 — B (gv*ca halo) in LDS, A (weights) frags direct from
// global (L2-resident, 16B-aligned in [o][tap*128+ci] layout). Barrier-free
// tap loop: 2 barriers per ci-half instead of 20.
#define BHI 0
#define BLO 17408
__global__ __launch_bounds__(256) void conv_mfma_kernel(
    const float* __restrict__ gv, const float* __restrict__ ca,
    const ushort_t* __restrict__ Whi, const ushort_t* __restrict__ Wlo,
    float* __restrict__ out)
{
    __shared__ char smem[34816];
    const int b   = blockIdx.z;
    const int h0  = blockIdx.y * 2;
    const int o0  = blockIdx.x * 64;
    const int tid = threadIdx.x;
    const int l   = tid & 63;
    const int wv  = tid >> 6;
    const int wy  = wv >> 1;
    const int wx  = wv & 1;
    const int ln  = l & 15;
    const int quad = l >> 4;

    f32x4 acc[2][2];
    #pragma unroll
    for (int i = 0; i < 2; ++i)
        #pragma unroll
        for (int j = 0; j < 2; ++j)
            acc[i][j] = (f32x4){0.f, 0.f, 0.f, 0.f};

    for (int half = 0; half < 2; ++half) {
        __syncthreads();   // protect B planes from readers of previous half
        for (int u = tid; u < 136 * 16; u += 256) {
            int p   = u >> 4;
            int ciq = u & 15;
            int hrel = p / 34;
            int c    = p - hrel * 34;
            int gr = h0 + hrel - 1;
            int gc = c - 1;
            bool ok = ((unsigned)gr < 32u) && ((unsigned)gc < 32u);
            int cib = half * 64 + ciq * 4;
            unsigned int hx = 0, hy = 0, lx = 0, ly = 0;
            #pragma unroll
            for (int t = 0; t < 4; ++t) {
                float v = 0.0f;
                if (ok)
                    v = gv[(size_t)(b * CI_ + cib + t) * N_ + gr * 32 + gc]
                        * ca[b * CI_ + cib + t];
                unsigned short h = f2bf_rne(v);
                unsigned short lo = f2bf_rne(v - bf2f(h));
                if (t < 2) { hx |= ((unsigned)h) << (16 * t); lx |= ((unsigned)lo) << (16 * t); }
                else       { hy |= ((unsigned)h) << (16 * (t - 2)); ly |= ((unsigned)lo) << (16 * (t - 2)); }
            }
            int addr = p * 128 + (((ciq >> 1) ^ (p & 7)) << 4) + ((ciq & 1) << 3);
            *(uint2*)&smem[BHI + addr] = make_uint2(hx, hy);
            *(uint2*)&smem[BLO + addr] = make_uint2(lx, ly);
        }
        __syncthreads();

        for (int tap = 0; tap < 9; ++tap) {
            const int dy = tap / 3, dx = tap - dy * 3;
            const int pbase = (wx + dy) * 34 + dx;
            #pragma unroll
            for (int cc = 0; cc < 2; ++cc) {
                v8bf Bh[2], Bl[2], Ah[2], Al[2];
                #pragma unroll
                for (int i = 0; i < 2; ++i) {
                    size_t aoff = (size_t)(o0 + wy * 32 + i * 16 + ln) * 1152
                                + tap * 128 + half * 64 + cc * 32 + quad * 8;
                    Ah[i] = ld8(Whi + aoff);
                    Al[i] = ld8(Wlo + aoff);
                }
                #pragma unroll
                for (int j = 0; j < 2; ++j) {
                    int p = pbase + j * 16 + ln;
                    int ch = cc * 4 + quad;
                    int addr = p * 128 + ((ch ^ (p & 7)) << 4);
                    Bh[j] = *(const v8bf*)&smem[BHI + addr];
                    Bl[j] = *(const v8bf*)&smem[BLO + addr];
                }
                #pragma unroll
                for (int i = 0; i < 2; ++i)
                    #pragma unroll
                    for (int j = 0; j < 2; ++j) {
                        acc[i][j] = __builtin_amdgcn_mfma_f32_16x16x32_bf16(Ah[i], Bh[j], acc[i][j], 0, 0, 0);
                        acc[i][j] = __builtin_amdgcn_mfma_f32_16x16x32_bf16(Ah[i], Bl[j], acc[i][j], 0, 0, 0);
                        acc[i][j] = __builtin_amdgcn_mfma_f32_16x16x32_bf16(Al[i], Bh[j], acc[i][j], 0, 0, 0);
                    }
            }
        }
    }

    const int h = h0 + wx;
    #pragma unroll
    for (int i = 0; i < 2; ++i)
        #pragma unroll
        for (int j = 0; j < 2; ++j)
            #pragma unroll
            for (int r = 0; r < 4; ++r) {
                int o = o0 + wy * 32 + i * 16 + quad * 4 + r;
                int w = j * 16 + ln;
                out[(size_t)(b * CO_ + o) * N_ + h * 32 + w] = acc[i][j][r];
            }
}

// ---------------------------------------------------------------------------
extern "C" void kernel_launch(void* const* d_in, const int* in_sizes, int n_in,
                              void* d_out, int out_size, void* d_ws, size_t ws_size,
                              hipStream_t stream) {
    const float* x   = (const float*)d_in[0];
    const float* Wq  = (const float*)d_in[1];
    const float* Wk  = (const float*)d_in[2];
    const float* Wv  = (const float*)d_in[3];
    const float* w1d = (const float*)d_in[4];
    const float* Wc  = (const float*)d_in[5];

    float* out  = (float*)d_out;
    float* gate = out + 2097152;
    float* ca   = gate + 8388608;

    float*    gv      = (float*)d_ws;            // 1048576 f
    float*    meanb   = gv + 1048576;            // 1024 f
    ushort_t* Whi     = (ushort_t*)(meanb + 1024);   // 294912
    ushort_t* Wlo     = Whi + 294912;
    ushort_t* Wp_hi   = Wlo + 294912;            // 98304
    ushort_t* Wp_lo   = Wp_hi + 98304;
    ushort_t* xs_hi   = Wp_lo + 98304;           // 2097152
    ushort_t* xs_lo   = xs_hi + 2097152;
    ushort_t* qt_hi   = xs_lo + 2097152;         // 1048576
    ushort_t* qt_lo   = qt_hi + 1048576;
    ushort_t* kt_hi   = qt_lo + 1048576;
    ushort_t* kt_lo   = kt_hi + 1048576;
    ushort_t* vB_hi   = kt_lo + 1048576;         // 1048576 (packed [b][m>>5][c][m&31])
    ushort_t* vB_lo   = vB_hi + 1048576;

    prep_w_kernel<<<dim3(1536), 256, 0, stream>>>(Wc, Wq, Wk, Wv, Whi, Wlo, Wp_hi, Wp_lo);
    prep_x_kernel<<<dim3(32, 8), 256, 0, stream>>>(x, xs_hi, xs_lo);
    hipMemsetAsync(meanb, 0, 1024 * sizeof(float), stream);
    proj_mfma_kernel<<<dim3(16, 6, 8), 256, 0, stream>>>(
        Wp_hi, Wp_lo, xs_hi, xs_lo, qt_hi, qt_lo, kt_hi, kt_lo, vB_hi, vB_lo);
    attn_fused_kernel<<<dim3(64, 8), 256, 0, stream>>>(
        qt_hi, qt_lo, kt_hi, kt_lo, vB_hi, vB_lo, gate, gv, meanb);
    ca_kernel<<<1, 1024, 0, stream>>>(meanb, w1d, ca);
    conv_mfma_kernel<<<dim3(4, 16, 8), 256, 0, stream>>>(gv, ca, Whi, Wlo, out);
}